// Round 5
// baseline (276.247 us; speedup 1.0000x reference)
//
#include <hip/hip_runtime.h>
#include <hip/hip_fp16.h>

// Problem constants (B=4, S=8192, IN=OUT=1024, GROUP=128)
#define K_DIM 1024
#define N_DIM 1024

typedef int v4i __attribute__((ext_vector_type(4)));

__device__ __forceinline__ void async_load16(const void* g, void* l) {
    __builtin_amdgcn_global_load_lds(
        (const __attribute__((address_space(1))) unsigned int*)g,
        (__attribute__((address_space(3))) unsigned int*)l,
        16, 0, 0);
}

// Raw barrier: no compiler-forced vmcnt(0) drain. "memory" clobbers pin
// LDS/global *instructions* (completion is handled by explicit waitcnts).
#define BAR() do { asm volatile("" ::: "memory"); \
                   __builtin_amdgcn_s_barrier();  \
                   asm volatile("" ::: "memory"); } while (0)

// ---------------- Kernel A: fused weight prep + activation quant -----------
// Blocks [0,256): prep_w (1024 rows / 4 per block).
// Blocks [256, 256+8192): quant_x (32768 rows / 4 per block).
// ~30 us, ~roofline for its 165 MB of traffic. Unchanged.
__global__ __launch_bounds__(256) void prep_quant(const float* __restrict__ w,
                                                  const float* __restrict__ x,
                                                  signed char* __restrict__ wq,
                                                  float* __restrict__ wscale,
                                                  signed char* __restrict__ xq,
                                                  float* __restrict__ xs) {
    const int lane = threadIdx.x & 63;
    if (blockIdx.x < 256) {
        const int row = blockIdx.x * 4 + (threadIdx.x >> 6);
        const float4* wr = (const float4*)(w + (size_t)row * K_DIM);
        float4 v[4];
#pragma unroll
        for (int j = 0; j < 4; ++j) v[j] = wr[lane * 4 + j];

        float g = 0.f;
#pragma unroll
        for (int j = 0; j < 4; ++j) {
            g = fmaxf(g, fabsf(v[j].x)); g = fmaxf(g, fabsf(v[j].y));
            g = fmaxf(g, fabsf(v[j].z)); g = fmaxf(g, fabsf(v[j].w));
        }
        g = fmaxf(g, __shfl_xor(g, 1, 64));
        g = fmaxf(g, __shfl_xor(g, 2, 64));
        g = fmaxf(g, __shfl_xor(g, 4, 64));
        const float s = __half2float(__float2half(fmaxf(g, 1e-8f)));
        float t = s;
        t += __shfl_xor(t, 8, 64);
        t += __shfl_xor(t, 16, 64);
        t += __shfl_xor(t, 32, 64);
        if (lane == 0) wscale[row] = t * 0.125f;

        int pk[4];
#pragma unroll
        for (int j = 0; j < 4; ++j) {
            const int b0 = (v[j].x > 0.f) ? 1 : -1;
            const int b1 = (v[j].y > 0.f) ? 1 : -1;
            const int b2 = (v[j].z > 0.f) ? 1 : -1;
            const int b3 = (v[j].w > 0.f) ? 1 : -1;
            pk[j] = (b0 & 255) | ((b1 & 255) << 8) | ((b2 & 255) << 16) | (b3 << 24);
        }
        *(int4*)(wq + (size_t)row * K_DIM + lane * 16) = make_int4(pk[0], pk[1], pk[2], pk[3]);
    } else {
        const int row = (blockIdx.x - 256) * 4 + (threadIdx.x >> 6);
        const float4* xr = (const float4*)(x + (size_t)row * K_DIM);
        float4 v[4];
#pragma unroll
        for (int j = 0; j < 4; ++j) v[j] = xr[lane * 4 + j];

        float am = 0.f;
#pragma unroll
        for (int j = 0; j < 4; ++j) {
            am = fmaxf(am, fabsf(v[j].x)); am = fmaxf(am, fabsf(v[j].y));
            am = fmaxf(am, fabsf(v[j].z)); am = fmaxf(am, fabsf(v[j].w));
        }
#pragma unroll
        for (int off = 32; off >= 1; off >>= 1) am = fmaxf(am, __shfl_xor(am, off, 64));
        const float scale = fmaxf(am, 1e-8f) / 127.f;
        const float inv   = 1.0f / scale;   // wave-uniform, one divide

        int pk[4];
#pragma unroll
        for (int j = 0; j < 4; ++j) {
            const int b0 = (int)fminf(fmaxf(rintf(v[j].x * inv), -128.f), 127.f);
            const int b1 = (int)fminf(fmaxf(rintf(v[j].y * inv), -128.f), 127.f);
            const int b2 = (int)fminf(fmaxf(rintf(v[j].z * inv), -128.f), 127.f);
            const int b3 = (int)fminf(fmaxf(rintf(v[j].w * inv), -128.f), 127.f);
            pk[j] = (b0 & 255) | ((b1 & 255) << 8) | ((b2 & 255) << 16) | (b3 << 24);
        }
        *(int4*)(xq + (size_t)row * K_DIM + lane * 16) = make_int4(pk[0], pk[1], pk[2], pk[3]);
        if (lane == 0) xs[row] = scale;
    }
}

// ---------------- Kernel B: int8 GEMM, 128x128, double-buffer, 4 blocks/CU --
// 256 thr (4 waves 2x2), wave tile 64x64 = acc[4][4], BK=64.
// LDS: 2 x (128x64) x {A,B} = 32 KiB; __launch_bounds__(256,4) caps VGPR at
// 128 -> 4 blocks/CU = 16 waves (was 12). Occupancy is the lever this round:
// rounds 0/1/4 showed three different pipeline depths all ~75 us, while the
// round-2 profile (MfmaUtil 12%, VALUBusy 13%, all pipes idle) fingerprints
// latency-boundedness.
// T3-minimum schedule per K-step: vmcnt(0) -> barrier -> STAGE(t+1, other
// buf) -> ds_read+MFMA(t) -> lgkm drain. Stage issued EARLY, waited at the
// top of the next step: one full compute phase (~800+ cy wall at 4 waves/
// SIMD) of cover > L2 latency (A is L2-resident via XCD swizzle, B L2-hot).
// Hazard-free: readers of buf[(t+1)&1] (step t-1) drained their ds_reads
// (lgkmcnt(0)) before BAR(t); staging lands after BAR(t).
// STAGING HW RULE (m104/m108): LDS dest = wave-uniform base + lane*16 ->
// dest tid*16, 4KB/call = 64 rows x 64B; row = tid>>2, phys chunk = tid&3.
// Swizzle: phys chunk = logical chunk ^ (row&3) applied on the GLOBAL source
// (dest linear) and on ds_read addresses -- same involution (rule #21).
__global__ __launch_bounds__(256, 4) void gemm_i8(const signed char* __restrict__ A,
                                                  const signed char* __restrict__ Bw,
                                                  const float* __restrict__ xs,
                                                  const float* __restrict__ wscale,
                                                  const float* __restrict__ bias,
                                                  float* __restrict__ out) {
    __shared__ __align__(16) signed char As[2][128 * 64];
    __shared__ __align__(16) signed char Bs[2][128 * 64];

    const int tid  = threadIdx.x;
    const int lane = tid & 63;
    const int wave = tid >> 6;
    const int wm = wave >> 1;   // 0..1
    const int wn = wave & 1;    // 0..1

    // XCD-aware mapping: XCD owns 32 m-tiles x 8 n-tiles so an A-panel lands
    // in one XCD's L2 and is reused for all 8 n-tiles.
    const int bid = blockIdx.x;
    const int xcd = bid & 7;
    const int q   = bid >> 3;            // 0..255
    const int mT  = xcd * 32 + (q >> 3); // 0..255
    const int nT  = q & 7;
    const size_t mBase = (size_t)mT * 128;
    const int    nBase = nT * 128;

    // staging: row = tid>>2, phys chunk = tid&3, source col inverse-swizzled.
    const int srow = tid >> 2;                              // 0..63
    const int scol = ((tid & 3) ^ (srow & 3)) * 16;         // logical source col
    const int soff = tid * 16;                              // linear LDS dest
    const signed char* Ag = A  + (mBase + srow) * K_DIM + scol;
    const signed char* Bg = Bw + (size_t)(nBase + srow) * K_DIM + scol;

#define STAGE(b, kt) do {                                                \
        const int _ko = (kt) * 64;                                       \
        async_load16(Ag + _ko,                      As[b] + soff);       \
        async_load16(Ag + (size_t)64 * K_DIM + _ko, As[b] + 4096 + soff);\
        async_load16(Bg + _ko,                      Bs[b] + soff);       \
        async_load16(Bg + (size_t)64 * K_DIM + _ko, Bs[b] + 4096 + soff);\
    } while (0)

    v4i acc[4][4] = {};
    const int r16 = lane & 15;
    const int g   = lane >> 4;                 // logical 16B k-chunk, 0..3
    const int co  = (g ^ (r16 & 3)) * 16;      // swizzled phys offset (row&3 == r16&3)

    STAGE(0, 0);

    for (int t = 0; t < 16; ++t) {
        // tile t's 4 loads are the only outstanding VMEM ops; issued one full
        // compute phase ago (prologue for t=0).
        asm volatile("s_waitcnt vmcnt(0)" ::: "memory");
        BAR();
        if (t < 15) STAGE((t + 1) & 1, t + 1);   // into buffer last read at t-1

        const signed char* Ab = As[t & 1];
        const signed char* Bb = Bs[t & 1];
        v4i af[4], bf[4];
#pragma unroll
        for (int mf = 0; mf < 4; ++mf)
            af[mf] = *(const v4i*)(Ab + ((wm * 64 + mf * 16 + r16) << 6) + co);
#pragma unroll
        for (int nf = 0; nf < 4; ++nf)
            bf[nf] = *(const v4i*)(Bb + ((wn * 64 + nf * 16 + r16) << 6) + co);

#pragma unroll
        for (int mf = 0; mf < 4; ++mf)
#pragma unroll
            for (int nf = 0; nf < 4; ++nf)
                acc[mf][nf] = __builtin_amdgcn_mfma_i32_16x16x64_i8(
                    af[mf], bf[nf], acc[mf][nf], 0, 0, 0);

        // pin instruction order (rule #18), then require this wave's ds_reads
        // complete before it can cross the next barrier (after which other
        // waves' staging overwrites this buffer).
        __builtin_amdgcn_sched_barrier(0);
        asm volatile("s_waitcnt lgkmcnt(0)" ::: "memory");
    }
#undef STAGE

    // epilogue: C/D layout col = lane&15, row = (lane>>4)*4 + reg
    const int cc = r16;
    const int rq = (lane >> 4) * 4;
    float xsr[4][4];   // loaded post-loop: no register lifetime across K-loop
#pragma unroll
    for (int mf = 0; mf < 4; ++mf)
#pragma unroll
        for (int i = 0; i < 4; ++i)
            xsr[mf][i] = xs[mBase + wm * 64 + mf * 16 + rq + i];

#pragma unroll
    for (int nf = 0; nf < 4; ++nf) {
        const int col   = nBase + wn * 64 + nf * 16 + cc;
        const float wsc = wscale[col];
        const float bb  = bias[col];
#pragma unroll
        for (int mf = 0; mf < 4; ++mf) {
#pragma unroll
            for (int i = 0; i < 4; ++i) {
                const size_t row = mBase + wm * 64 + mf * 16 + rq + i;
                out[row * N_DIM + col] = (float)acc[mf][nf][i] * xsr[mf][i] * wsc + bb;
            }
        }
    }
}

extern "C" void kernel_launch(void* const* d_in, const int* in_sizes, int n_in,
                              void* d_out, int out_size, void* d_ws, size_t ws_size,
                              hipStream_t stream) {
    const float* x    = (const float*)d_in[0];
    const float* w    = (const float*)d_in[1];
    const float* bias = (const float*)d_in[2];
    float* out = (float*)d_out;

    const int BT = in_sizes[0] / K_DIM;  // 32768 tokens

    // workspace carve
    char* ws = (char*)d_ws;
    signed char* xq     = (signed char*)ws;                                          // BT*1024 B
    float*       xs     = (float*)(ws + (size_t)BT * K_DIM);                         // BT*4 B
    signed char* wq     = (signed char*)(ws + (size_t)BT * K_DIM + (size_t)BT * 4);  // 1 MB
    float*       wscale = (float*)((char*)wq + (size_t)N_DIM * K_DIM);               // 4 KB

    prep_quant<<<256 + BT / 4, 256, 0, stream>>>(w, x, wq, wscale, xq, xs);
    gemm_i8<<<(BT / 128) * (N_DIM / 128), 256, 0, stream>>>(xq, wq, xs, wscale, bias, out);
}